// Round 12
// baseline (241.698 us; speedup 1.0000x reference)
//
#include <hip/hip_runtime.h>

#define BATCH 8
#define SEQL 16384
#define NCH 128
#define NH 4
#define HD 32
#define GEPS 1e-5f

typedef __bf16 bf16x8 __attribute__((ext_vector_type(8)));
typedef __bf16 bf16x4 __attribute__((ext_vector_type(4)));
typedef float f32x4 __attribute__((ext_vector_type(4)));

// ---- workspace byte offsets ----
#define WKV_B   0          // 256*128 bf16 = 64 KiB   [o'][c], o' = o-128 (k:0..127, v:128..255)
#define WQ_B    65536      // 128*128 bf16 = 32 KiB   [o][c]
#define WO_B    98304      // 128*128 bf16 = 32 KiB   [o][c]
#define CTXB_B  131072     // 8*4*32*32 bf16 = 64 KiB [b][h][c][d]
#define GNS_B   196608     // 8*2 f32
#define CTXP_B  262144     // ctx partials [b*P + p][4096] f32 in [h][d][c] layout,
                           // then z [b*P + p][128] f32 (contiguous per block)

// LDS strides (bf16 units)
// xb: [kblk 4][qc 4][tok 64][ki 8]; qc-stride 520, kblk-stride 2088
// ekv (ONE 32-token slice): [qt 4][o 256][ti 8]; qt-stride 2056 — WAVE-PRIVATE rows:
//   wave h owns o in {h*32..h*32+31} (k) and {128+h*32..+31} (v) -> no inner barriers
// pB/attB (ALIASED): [h][dq 4][t 64][di 8]; dq-stride 520, h-stride 2088 — wave-private

__global__ void k_prep(const float* __restrict__ wqkv, const float* __restrict__ wout,
                       char* __restrict__ wsb) {
    int i = blockIdx.x * 256 + threadIdx.x;
    __bf16* wkvb = (__bf16*)(wsb + WKV_B);
    __bf16* wqb  = (__bf16*)(wsb + WQ_B);
    __bf16* wob  = (__bf16*)(wsb + WO_B);
    if (i < 384 * 128) {
        int o = i >> 7, c = i & 127;
        __bf16 v = (__bf16)wqkv[i];
        if (o < 128) wqb[o * 128 + c] = v;
        else         wkvb[(o - 128) * 128 + c] = v;
    }
    if (i < 128 * 128) wob[i] = (__bf16)wout[i];
    if (i < 16) ((float*)(wsb + GNS_B))[i] = 0.f;   // zero GN accumulators
}

// Pass 1: kv = Wkv @ x (MFMA); ek = exp(k); ctx_part = ek (outer) v (MFMA); Z_part.
// P=128, grid 1024 = exact 4-blocks/CU fill, nrep=2. HEAD-ALIGNED output tiling:
// wave h computes its OWN head's k rows (h*32..) and v rows (128+h*32..) -> the
// ekv write->read chain is wave-private, so the 2 inner barriers per half are gone
// (within-wave LDS ordering is program-order). Barriers/block: 8 -> 3.
__global__ __launch_bounds__(256, 4) void k_pass1(const float* __restrict__ x,
                                                  char* __restrict__ wsb, int P) {
    __shared__ __attribute__((aligned(16))) __bf16 xb[8352];
    __shared__ __attribute__((aligned(16))) __bf16 ekv[8232];   // one 32-token slice
    const int t = threadIdx.x;
    const int lane = t & 63, wave = t >> 6;
    const int n16 = lane & 15, q = lane >> 4;
    const int batch = blockIdx.x / P, sub = blockIdx.x % P;
    const int nrep = 256 / P;
    const __bf16* __restrict__ wkvb = (const __bf16*)(wsb + WKV_B);

    f32x4 ctxacc[2][2];
#pragma unroll
    for (int i = 0; i < 2; i++)
#pragma unroll
        for (int j = 0; j < 2; j++) ctxacc[i][j] = (f32x4){0.f, 0.f, 0.f, 0.f};
    float zacc[2][4];   // k-tiles mt=0,1 (this wave's head channels)
#pragma unroll
    for (int i = 0; i < 2; i++)
#pragma unroll
        for (int j = 0; j < 4; j++) zacc[i][j] = 0.f;

    for (int rep = 0; rep < nrep; rep++) {
        // stage chunk (all waves' xb reads of prev rep completed at its end-of-rep barrier)
        const int chunk = sub + rep * P;
        const float* xg = x + (size_t)(batch * SEQL + chunk * 64) * NCH;
#pragma unroll
        for (int r = 0; r < 8; r++) {
            int e = t + r * 256;
            int tok = e >> 5, c4 = (e & 31) * 4;
            float4 v = ((const float4*)xg)[e];
            bf16x4 h; h.x = (__bf16)v.x; h.y = (__bf16)v.y; h.z = (__bf16)v.z; h.w = (__bf16)v.w;
            *(bf16x4*)&xb[(c4 >> 5) * 2088 + ((c4 >> 3) & 3) * 520 + tok * 8 + (c4 & 7)] = h;
        }
        __syncthreads();   // B1: xb ready

#pragma unroll
        for (int half = 0; half < 2; half++) {
            // KV GEMM for this 32-token slice. Head-aligned row bases:
            // mt 0,1 -> k rows wave*32 + mt*16; mt 2,3 -> v rows 128 + wave*32 + (mt-2)*16
            f32x4 kvacc[4][2];
#pragma unroll
            for (int i = 0; i < 4; i++)
#pragma unroll
                for (int j = 0; j < 2; j++) kvacc[i][j] = (f32x4){0.f, 0.f, 0.f, 0.f};
#pragma unroll
            for (int ks = 0; ks < 4; ks++) {
                bf16x8 aw_k[4];
#pragma unroll
                for (int mt = 0; mt < 4; mt++) {
                    int ob = (mt < 2) ? (wave * 32 + mt * 16)
                                      : (128 + wave * 32 + (mt - 2) * 16);
                    aw_k[mt] = *(const bf16x8*)&wkvb[(ob + n16) * 128 + ks * 32 + q * 8];
                }
                bf16x8 b[2];
#pragma unroll
                for (int nl = 0; nl < 2; nl++)
                    b[nl] = *(const bf16x8*)&xb[ks * 2088 + q * 520 + ((half * 2 + nl) * 16 + n16) * 8];
#pragma unroll
                for (int mt = 0; mt < 4; mt++)
#pragma unroll
                    for (int nl = 0; nl < 2; nl++)
                        kvacc[mt][nl] = __builtin_amdgcn_mfma_f32_16x16x32_bf16(
                            aw_k[mt], b[nl], kvacc[mt][nl], 0, 0, 0);
            }
            // epilogue: mt<2 = own head's k channels (exp + Z); mt>=2 = own head's v.
            // ekv writes land in THIS wave's rows only — no barrier needed.
#pragma unroll
            for (int mt = 0; mt < 4; mt++) {
                int ob = (mt < 2) ? (wave * 32 + mt * 16)
                                  : (128 + wave * 32 + (mt - 2) * 16);
#pragma unroll
                for (int nl = 0; nl < 2; nl++) {
                    int ti = nl * 16 + n16;
                    int base = (ti >> 3) * 2056 + (ti & 7);
#pragma unroll
                    for (int r = 0; r < 4; r++) {
                        float vv = kvacc[mt][nl][r];
                        if (mt < 2) { vv = __expf(vv); zacc[mt][r] += vv; }
                        ekv[base + (ob + q * 4 + r) * 8] = (__bf16)vv;
                    }
                }
            }
            // ctx MFMA: reads ONLY this wave's ekv rows (RAW ordered by lgkmcnt)
            {
                bf16x8 ea[2], vb[2];
#pragma unroll
                for (int ml = 0; ml < 2; ml++) {
                    ea[ml] = *(const bf16x8*)&ekv[q * 2056 + (wave * 32 + ml * 16 + n16) * 8];
                    vb[ml] = *(const bf16x8*)&ekv[q * 2056 + (128 + wave * 32 + ml * 16 + n16) * 8];
                }
#pragma unroll
                for (int ml = 0; ml < 2; ml++)
#pragma unroll
                    for (int nl = 0; nl < 2; nl++)
                        ctxacc[ml][nl] = __builtin_amdgcn_mfma_f32_16x16x32_bf16(
                            ea[ml], vb[nl], ctxacc[ml][nl], 0, 0, 0);
            }
            // half-1 ekv overwrite is same-wave WAR: program order, no barrier
        }
        if (rep + 1 < nrep) __syncthreads();   // B2: all xb reads done before restage
    }

    // coalesced float4 flush, TRANSPOSED slab [h][d][c]
    float* ctxp = (float*)(wsb + CTXP_B) + (size_t)blockIdx.x * 4096 + wave * 1024;
#pragma unroll
    for (int nl = 0; nl < 2; nl++)
#pragma unroll
        for (int ml = 0; ml < 2; ml++) {
            float4 v4;
            v4.x = ctxacc[ml][nl][0]; v4.y = ctxacc[ml][nl][1];
            v4.z = ctxacc[ml][nl][2]; v4.w = ctxacc[ml][nl][3];
            *(float4*)&ctxp[(nl * 16 + n16) * 32 + ml * 16 + q * 4] = v4;
        }
    // contiguous z partial: z[block][o], o = wave*32 + mt*16 + q*4 + r (k channel)
    {
        float* zp = (float*)(wsb + CTXP_B) + (size_t)BATCH * P * 4096 + (size_t)blockIdx.x * 128;
#pragma unroll
        for (int mt = 0; mt < 2; mt++)
#pragma unroll
            for (int r = 0; r < 4; r++) {
                float z = zacc[mt][r];
                z += __shfl_xor(z, 1); z += __shfl_xor(z, 2);
                z += __shfl_xor(z, 4); z += __shfl_xor(z, 8);
                if (n16 == 0) zp[wave * 32 + mt * 16 + q * 4 + r] = z;
            }
    }
}

// Parallel reduce + normalize. ctx slabs are [h][d][c]; ctxb write un-transposes to
// [b][h][c][d]. z is [p][o]-contiguous; transpose absorbed via an 8x32 LDS reduction.
__global__ __launch_bounds__(256) void k_reduce(char* __restrict__ wsb, int P) {
    __shared__ float red[4][64];
    __shared__ float zred[8][33];
    const int tid = threadIdx.x;
    const int b = blockIdx.x >> 6, eg = blockIdx.x & 63;   // h = eg>>4
    const float* ctxp = (const float*)(wsb + CTXP_B);
    const float* zp = ctxp + (size_t)BATCH * P * 4096;

    // z sums: 8 p-slots x 32 channels (this block's h-group)
    {
        int ci = tid & 31, pslot = tid >> 5;
        int ho = (eg >> 4) * 32;
        float zs = 0.f;
        for (int p = pslot; p < P; p += 8)
            zs += zp[(size_t)(b * P + p) * 128 + ho + ci];
        zred[pslot][ci] = zs;
    }
    // ctx partial sums: thread (pg, e) sums P/4 slabs, coalesced across e
    {
        int pg = tid >> 6, e = tid & 63;
        int cnt = P >> 2;
        const float* base = ctxp + ((size_t)(b * P + pg * cnt)) * 4096 + eg * 64 + e;
        float cs = 0.f;
        for (int k = 0; k < cnt; k++) cs += base[(size_t)k * 4096];
        red[pg][e] = cs;
    }
    __syncthreads();
    if (tid < 64) {
        float tot = red[0][tid] + red[1][tid] + red[2][tid] + red[3][tid];
        int c = tid & 31;
        float zs = 0.f;
#pragma unroll
        for (int s = 0; s < 8; s++) zs += zred[s][c];
        int e = eg * 64 + tid;
        int h = e >> 10, d = (e >> 5) & 31;
        ((__bf16*)(wsb + CTXB_B))[((size_t)b << 12) + (h << 10) + (c << 5) + d] =
            (__bf16)(tot / zs);
    }
}

// Pass 2: q = Wq @ x; reg softmax; attn = ctx @ p; out = Wout @ attn + bias; GN sums.
// Grid 1024, nrep=2. attB now aliases pB (both wave-private regions) instead of xb:
// pB write -> attn read -> attB write is all same-wave program order, so the old B2
// disappears; xb is only touched by staging + Wq GEMM, so restaging can start right
// after B3 (which transitively orders all waves' xb reads). Barriers/rep: 4 -> 2.
__global__ __launch_bounds__(256, 4) void k_pass2(const float* __restrict__ x,
                                                  const float* __restrict__ bout,
                                                  char* __restrict__ wsb,
                                                  float* __restrict__ out) {
    __shared__ __attribute__((aligned(16))) __bf16 xb[8352];
    __shared__ __attribute__((aligned(16))) __bf16 pB[8352];   // reused as attB
    __shared__ float gred[8];
    const int t = threadIdx.x;
    const int lane = t & 63, wave = t >> 6;       // wave == head h
    const int n16 = lane & 15, q = lane >> 4;
    const int batch = blockIdx.x >> 7, sub = blockIdx.x & 127;
    const __bf16* __restrict__ wqb = (const __bf16*)(wsb + WQ_B);
    const __bf16* __restrict__ wob = (const __bf16*)(wsb + WO_B);
    const __bf16* __restrict__ ctxb = (const __bf16*)(wsb + CTXB_B);

    bf16x8 actx[2];
#pragma unroll
    for (int ml = 0; ml < 2; ml++)
        actx[ml] = *(const bf16x8*)&ctxb[((size_t)(batch * 4 + wave) * 32 + ml * 16 + n16) * 32 + q * 8];
    float4 bias[2];
#pragma unroll
    for (int ml = 0; ml < 2; ml++)
        bias[ml] = *(const float4*)&bout[wave * 32 + ml * 16 + q * 4];

    // prologue: stage chunk 'sub'
    {
        const float* xg = x + (size_t)(batch * SEQL + sub * 64) * NCH;
#pragma unroll
        for (int r = 0; r < 8; r++) {
            int e = t + r * 256;
            int tok = e >> 5, c4 = (e & 31) * 4;
            float4 v = ((const float4*)xg)[e];
            bf16x4 h; h.x = (__bf16)v.x; h.y = (__bf16)v.y; h.z = (__bf16)v.z; h.w = (__bf16)v.w;
            *(bf16x4*)&xb[(c4 >> 5) * 2088 + ((c4 >> 3) & 3) * 520 + tok * 8 + (c4 & 7)] = h;
        }
    }

    float s1 = 0.f, s2 = 0.f;
    bf16x4 hpre[8];

#pragma unroll
    for (int rep = 0; rep < 2; rep++) {
        const int chunk = sub + rep * 128;
        const size_t tok0 = (size_t)batch * SEQL + chunk * 64;
        __syncthreads();                    // B1: xb(rep) ready; prev rep's attB reads done
        f32x4 qacc[2][4];
#pragma unroll
        for (int i = 0; i < 2; i++)
#pragma unroll
            for (int j = 0; j < 4; j++) qacc[i][j] = (f32x4){0.f, 0.f, 0.f, 0.f};
#pragma unroll
        for (int ks = 0; ks < 4; ks++) {
            bf16x8 aq_k[2];
#pragma unroll
            for (int ml = 0; ml < 2; ml++)
                aq_k[ml] = *(const bf16x8*)&wqb[(wave * 32 + ml * 16 + n16) * 128 + ks * 32 + q * 8];
            bf16x8 b[4];
#pragma unroll
            for (int nt = 0; nt < 4; nt++)
                b[nt] = *(const bf16x8*)&xb[ks * 2088 + q * 520 + (nt * 16 + n16) * 8];
#pragma unroll
            for (int ml = 0; ml < 2; ml++)
#pragma unroll
                for (int nt = 0; nt < 4; nt++)
                    qacc[ml][nt] = __builtin_amdgcn_mfma_f32_16x16x32_bf16(
                        aq_k[ml], b[nt], qacc[ml][nt], 0, 0, 0);
        }
        // prefetch rep-1 x; loads land during softmax
        float4 vpre[8];
        if (rep == 0) {
            const float* xg2 = x + (size_t)(batch * SEQL + (sub + 128) * 64) * NCH;
#pragma unroll
            for (int r = 0; r < 8; r++) vpre[r] = ((const float4*)xg2)[t + r * 256];
        }
#pragma unroll
        for (int nt = 0; nt < 4; nt++) {
            float ss = 0.f;
#pragma unroll
            for (int ml = 0; ml < 2; ml++)
#pragma unroll
                for (int r = 0; r < 4; r++) {
                    float e = __expf(qacc[ml][nt][r]);
                    qacc[ml][nt][r] = e;
                    ss += e;
                }
            ss += __shfl_xor(ss, 16);
            ss += __shfl_xor(ss, 32);
            float inv = 0.17677669529663687f / ss;   // (1/sqrt(32)) / denom
#pragma unroll
            for (int ml = 0; ml < 2; ml++)
#pragma unroll
                for (int r = 0; r < 4; r++) qacc[ml][nt][r] *= inv;
        }
        if (rep == 0) {                     // shrink f32->bf16 early (liveness)
#pragma unroll
            for (int r = 0; r < 8; r++) {
                bf16x4 h;
                h.x = (__bf16)vpre[r].x; h.y = (__bf16)vpre[r].y;
                h.z = (__bf16)vpre[r].z; h.w = (__bf16)vpre[r].w;
                hpre[r] = h;
            }
        }
        // p -> own pB region (no barrier needed before attn: same-wave RAW)
#pragma unroll
        for (int ml = 0; ml < 2; ml++)
#pragma unroll
            for (int nt = 0; nt < 4; nt++) {
                bf16x4 h;
                h.x = (__bf16)qacc[ml][nt][0]; h.y = (__bf16)qacc[ml][nt][1];
                h.z = (__bf16)qacc[ml][nt][2]; h.w = (__bf16)qacc[ml][nt][3];
                *(bf16x4*)&pB[wave * 2088 + (ml * 2 + (q >> 1)) * 520 +
                              (nt * 16 + n16) * 8 + (q & 1) * 4] = h;
            }
        // attn MFMA: A = ctx[h] (regs), B = own pB region
        f32x4 aacc[2][4];
#pragma unroll
        for (int ml = 0; ml < 2; ml++)
#pragma unroll
            for (int nt = 0; nt < 4; nt++) {
                bf16x8 pb = *(const bf16x8*)&pB[wave * 2088 + q * 520 + (nt * 16 + n16) * 8];
                aacc[ml][nt] = __builtin_amdgcn_mfma_f32_16x16x32_bf16(
                    actx[ml], pb, (f32x4){0.f, 0.f, 0.f, 0.f}, 0, 0, 0);
            }
        // attn -> attB (= pB, own region; same-wave WAR after the pb reads)
        __bf16* attB = pB;
#pragma unroll
        for (int ml = 0; ml < 2; ml++)
#pragma unroll
            for (int nt = 0; nt < 4; nt++) {
                bf16x4 h;
                h.x = (__bf16)aacc[ml][nt][0]; h.y = (__bf16)aacc[ml][nt][1];
                h.z = (__bf16)aacc[ml][nt][2]; h.w = (__bf16)aacc[ml][nt][3];
                *(bf16x4*)&attB[wave * 2088 + (ml * 2 + (q >> 1)) * 520 +
                                (nt * 16 + n16) * 8 + (q & 1) * 4] = h;
            }
        __syncthreads();                    // B3: all attB regions ready; xb reads done
        if (rep == 0) {                     // restage xb now — overlaps Wout GEMM
#pragma unroll
            for (int r = 0; r < 8; r++) {
                int e = t + r * 256;
                int tok = e >> 5, c4 = (e & 31) * 4;
                *(bf16x4*)&xb[(c4 >> 5) * 2088 + ((c4 >> 3) & 3) * 520 + tok * 8 + (c4 & 7)] = hpre[r];
            }
        }
        f32x4 oacc[2][4];
#pragma unroll
        for (int i = 0; i < 2; i++)
#pragma unroll
            for (int j = 0; j < 4; j++) oacc[i][j] = (f32x4){0.f, 0.f, 0.f, 0.f};
#pragma unroll
        for (int ks = 0; ks < 4; ks++) {
            bf16x8 ao_k[2];
#pragma unroll
            for (int ml = 0; ml < 2; ml++)
                ao_k[ml] = *(const bf16x8*)&wob[(wave * 32 + ml * 16 + n16) * 128 + ks * 32 + q * 8];
            bf16x8 b[4];
#pragma unroll
            for (int nt = 0; nt < 4; nt++)
                b[nt] = *(const bf16x8*)&attB[ks * 2088 + q * 520 + (nt * 16 + n16) * 8];
#pragma unroll
            for (int ml = 0; ml < 2; ml++)
#pragma unroll
                for (int nt = 0; nt < 4; nt++)
                    oacc[ml][nt] = __builtin_amdgcn_mfma_f32_16x16x32_bf16(
                        ao_k[ml], b[nt], oacc[ml][nt], 0, 0, 0);
        }
#pragma unroll
        for (int ml = 0; ml < 2; ml++)
#pragma unroll
            for (int nt = 0; nt < 4; nt++) {
                float4 vv;
                vv.x = oacc[ml][nt][0] + bias[ml].x;
                vv.y = oacc[ml][nt][1] + bias[ml].y;
                vv.z = oacc[ml][nt][2] + bias[ml].z;
                vv.w = oacc[ml][nt][3] + bias[ml].w;
                s1 += vv.x + vv.y + vv.z + vv.w;
                s2 += vv.x * vv.x + vv.y * vv.y + vv.z * vv.z + vv.w * vv.w;
                *(float4*)&out[(tok0 + nt * 16 + n16) * NCH + wave * 32 + ml * 16 + q * 4] = vv;
            }
        // rep-1 pB writes are ordered behind other waves' attB reads by rep-1's B1
    }
#pragma unroll
    for (int off = 32; off > 0; off >>= 1) {
        s1 += __shfl_xor(s1, off);
        s2 += __shfl_xor(s2, off);
    }
    if (lane == 0) { gred[wave * 2 + 0] = s1; gred[wave * 2 + 1] = s2; }
    __syncthreads();
    if (t < 2) {
        float s = gred[t] + gred[2 + t] + gred[4 + t] + gred[6 + t];
        atomicAdd(&((float*)(wsb + GNS_B))[batch * 2 + t], s);
    }
}

// GroupNorm apply — proven form: 2x float4/thread, grid 8192.
__global__ __launch_bounds__(256) void k_gnorm(float* __restrict__ out,
                                               const char* __restrict__ wsb,
                                               const float* __restrict__ gw,
                                               const float* __restrict__ gb) {
    size_t base4 = ((size_t)blockIdx.x * 256 + threadIdx.x) * 2;   // float4 index
    int b = (int)(base4 >> 19);
    const float* gns = (const float*)(wsb + GNS_B);
    const float n = (float)NCH * (float)SEQL;
    float mean = gns[b * 2] / n;
    float var = gns[b * 2 + 1] / n - mean * mean;
    float rstd = rsqrtf(var + GEPS);
    int cbase = (int)((base4 & 31) * 4);
    float4 w0 = *(const float4*)&gw[cbase];
    float4 w1 = *(const float4*)&gw[cbase + 4];
    float4 b0 = *(const float4*)&gb[cbase];
    float4 b1 = *(const float4*)&gb[cbase + 4];
    float4 v0 = ((float4*)out)[base4];
    float4 v1 = ((float4*)out)[base4 + 1];
    v0.x = (v0.x - mean) * rstd * w0.x + b0.x;
    v0.y = (v0.y - mean) * rstd * w0.y + b0.y;
    v0.z = (v0.z - mean) * rstd * w0.z + b0.z;
    v0.w = (v0.w - mean) * rstd * w0.w + b0.w;
    v1.x = (v1.x - mean) * rstd * w1.x + b1.x;
    v1.y = (v1.y - mean) * rstd * w1.y + b1.y;
    v1.z = (v1.z - mean) * rstd * w1.z + b1.z;
    v1.w = (v1.w - mean) * rstd * w1.w + b1.w;
    ((float4*)out)[base4] = v0;
    ((float4*)out)[base4 + 1] = v1;
}

extern "C" void kernel_launch(void* const* d_in, const int* in_sizes, int n_in,
                              void* d_out, int out_size, void* d_ws, size_t ws_size,
                              hipStream_t stream) {
    const float* x    = (const float*)d_in[0];
    const float* wqkv = (const float*)d_in[1];
    const float* wout = (const float*)d_in[2];
    const float* bout = (const float*)d_in[3];
    const float* gw   = (const float*)d_in[4];
    const float* gb   = (const float*)d_in[5];
    float* out = (float*)d_out;
    char* wsb  = (char*)d_ws;

    int P = 128;
    while (P > 4 &&
           (size_t)CTXP_B + (size_t)BATCH * P * (16384 + 512) > ws_size)
        P >>= 1;

    k_prep<<<192, 256, 0, stream>>>(wqkv, wout, wsb);
    k_pass1<<<BATCH * P, 256, 0, stream>>>(x, wsb, P);
    k_reduce<<<BATCH * 64, 256, 0, stream>>>(wsb, P);
    k_pass2<<<1024, 256, 0, stream>>>(x, bout, wsb, out);
    k_gnorm<<<8192, 256, 0, stream>>>(out, wsb, gw, gb);
}

// Round 13
// 227.659 us; speedup vs baseline: 1.0617x; 1.0617x over previous
//
#include <hip/hip_runtime.h>

#define BATCH 8
#define SEQL 16384
#define NCH 128
#define NH 4
#define HD 32
#define GEPS 1e-5f

typedef __bf16 bf16x8 __attribute__((ext_vector_type(8)));
typedef __bf16 bf16x4 __attribute__((ext_vector_type(4)));
typedef float f32x4 __attribute__((ext_vector_type(4)));

// ---- workspace byte offsets ----
#define WKV_B   0          // 256*128 bf16 = 64 KiB   [o'][c], o' = o-128 (k:0..127, v:128..255)
#define WQ_B    65536      // 128*128 bf16 = 32 KiB   [o][c]
#define WO_B    98304      // 128*128 bf16 = 32 KiB   [o][c]
#define CTXB_B  131072     // 8*4*32*32 bf16 = 64 KiB [b][h][c][d]
#define GNS_B   196608     // 8*2 f32
#define CTXP_B  262144     // ctx partials [b*P + p][4096] f32 in [h][d][c] layout,
                           // then z [b*P + p][128] f32 (contiguous per block)

// LDS strides (bf16 units)
// xb: [kblk 4][qc 4][tok 64][ki 8]; qc-stride 520, kblk-stride 2088
// ekv (ONE 32-token slice): [qt 4][o 256][ti 8]; qt-stride 2056
// pB/attB: [h|ks 4][dq 4][t 64][di 8]; dq-stride 520, h-stride 2088

__global__ void k_prep(const float* __restrict__ wqkv, const float* __restrict__ wout,
                       char* __restrict__ wsb) {
    int i = blockIdx.x * 256 + threadIdx.x;
    __bf16* wkvb = (__bf16*)(wsb + WKV_B);
    __bf16* wqb  = (__bf16*)(wsb + WQ_B);
    __bf16* wob  = (__bf16*)(wsb + WO_B);
    if (i < 384 * 128) {
        int o = i >> 7, c = i & 127;
        __bf16 v = (__bf16)wqkv[i];
        if (o < 128) wqb[o * 128 + c] = v;
        else         wkvb[(o - 128) * 128 + c] = v;
    }
    if (i < 128 * 128) wob[i] = (__bf16)wout[i];
    if (i < 16) ((float*)(wsb + GNS_B))[i] = 0.f;   // zero GN accumulators
}

// Pass 1: kv = Wkv @ x (MFMA); ek = exp(k); ctx_part = ek (outer) v (MFMA); Z_part.
// P=128, grid 1024 = exact 4-blocks/CU fill, nrep=2. No register prefetch (spill risk
// at the 128-VGPR cap — round 8 lesson). The inner barriers double as scheduling
// fences that keep weight-load live ranges short (round 12 lesson: removing them
// spilled). Stage at loop top; 16 waves/CU TLP hide it.
__global__ __launch_bounds__(256, 4) void k_pass1(const float* __restrict__ x,
                                                  char* __restrict__ wsb, int P) {
    __shared__ __attribute__((aligned(16))) __bf16 xb[8352];
    __shared__ __attribute__((aligned(16))) __bf16 ekv[8232];   // one 32-token slice
    const int t = threadIdx.x;
    const int lane = t & 63, wave = t >> 6;
    const int n16 = lane & 15, q = lane >> 4;
    const int batch = blockIdx.x / P, sub = blockIdx.x % P;
    const int nrep = 256 / P;
    const __bf16* __restrict__ wkvb = (const __bf16*)(wsb + WKV_B);

    f32x4 ctxacc[2][2];
#pragma unroll
    for (int i = 0; i < 2; i++)
#pragma unroll
        for (int j = 0; j < 2; j++) ctxacc[i][j] = (f32x4){0.f, 0.f, 0.f, 0.f};
    float zacc[2][4];   // k-tiles mt=0,1
#pragma unroll
    for (int i = 0; i < 2; i++)
#pragma unroll
        for (int j = 0; j < 4; j++) zacc[i][j] = 0.f;

    for (int rep = 0; rep < nrep; rep++) {
        // stage chunk (xb reads of prev rep all completed at its E1(half1) barrier)
        const int chunk = sub + rep * P;
        const float* xg = x + (size_t)(batch * SEQL + chunk * 64) * NCH;
#pragma unroll
        for (int r = 0; r < 8; r++) {
            int e = t + r * 256;
            int tok = e >> 5, c4 = (e & 31) * 4;
            float4 v = ((const float4*)xg)[e];
            bf16x4 h; h.x = (__bf16)v.x; h.y = (__bf16)v.y; h.z = (__bf16)v.z; h.w = (__bf16)v.w;
            *(bf16x4*)&xb[(c4 >> 5) * 2088 + ((c4 >> 3) & 3) * 520 + tok * 8 + (c4 & 7)] = h;
        }
        __syncthreads();   // B1: xb ready; prev rep's ekv reads complete

#pragma unroll
        for (int half = 0; half < 2; half++) {
            // KV GEMM for this 32-token slice: D[o][t], o = mt*64 + wave*16 + row
            f32x4 kvacc[4][2];
#pragma unroll
            for (int i = 0; i < 4; i++)
#pragma unroll
                for (int j = 0; j < 2; j++) kvacc[i][j] = (f32x4){0.f, 0.f, 0.f, 0.f};
#pragma unroll
            for (int ks = 0; ks < 4; ks++) {
                bf16x8 aw_k[4];
#pragma unroll
                for (int mt = 0; mt < 4; mt++)
                    aw_k[mt] = *(const bf16x8*)&wkvb[(mt * 64 + wave * 16 + n16) * 128 + ks * 32 + q * 8];
                bf16x8 b[2];
#pragma unroll
                for (int nl = 0; nl < 2; nl++)
                    b[nl] = *(const bf16x8*)&xb[ks * 2088 + q * 520 + ((half * 2 + nl) * 16 + n16) * 8];
#pragma unroll
                for (int mt = 0; mt < 4; mt++)
#pragma unroll
                    for (int nl = 0; nl < 2; nl++)
                        kvacc[mt][nl] = __builtin_amdgcn_mfma_f32_16x16x32_bf16(
                            aw_k[mt], b[nl], kvacc[mt][nl], 0, 0, 0);
            }
            // epilogue: mt<2 are k-channels (exp + Z) on EVERY wave; mt>=2 are v
#pragma unroll
            for (int mt = 0; mt < 4; mt++)
#pragma unroll
                for (int nl = 0; nl < 2; nl++) {
                    int ti = nl * 16 + n16;
                    int base = (ti >> 3) * 2056 + (ti & 7);
#pragma unroll
                    for (int r = 0; r < 4; r++) {
                        float vv = kvacc[mt][nl][r];
                        if (mt < 2) { vv = __expf(vv); zacc[mt][r] += vv; }
                        int o = mt * 64 + wave * 16 + q * 4 + r;
                        ekv[base + o * 8] = (__bf16)vv;
                    }
                }
            __syncthreads();   // E1: ekv slice ready; all xb reads of this half done
            // ctx MFMA: wave = head h; A = ek[h*32+c][ti], B = v[h*32+d][ti]
            {
                bf16x8 ea[2], vb[2];
#pragma unroll
                for (int ml = 0; ml < 2; ml++) {
                    ea[ml] = *(const bf16x8*)&ekv[q * 2056 + (wave * 32 + ml * 16 + n16) * 8];
                    vb[ml] = *(const bf16x8*)&ekv[q * 2056 + (128 + wave * 32 + ml * 16 + n16) * 8];
                }
#pragma unroll
                for (int ml = 0; ml < 2; ml++)
#pragma unroll
                    for (int nl = 0; nl < 2; nl++)
                        ctxacc[ml][nl] = __builtin_amdgcn_mfma_f32_16x16x32_bf16(
                            ea[ml], vb[nl], ctxacc[ml][nl], 0, 0, 0);
            }
            if (half == 0) __syncthreads();   // E2: slice reads done before overwrite
        }
    }

    // coalesced float4 flush, TRANSPOSED slab [h][d][c]
    float* ctxp = (float*)(wsb + CTXP_B) + (size_t)blockIdx.x * 4096 + wave * 1024;
#pragma unroll
    for (int nl = 0; nl < 2; nl++)
#pragma unroll
        for (int ml = 0; ml < 2; ml++) {
            float4 v4;
            v4.x = ctxacc[ml][nl][0]; v4.y = ctxacc[ml][nl][1];
            v4.z = ctxacc[ml][nl][2]; v4.w = ctxacc[ml][nl][3];
            *(float4*)&ctxp[(nl * 16 + n16) * 32 + ml * 16 + q * 4] = v4;
        }
    // contiguous z partial: z[block][o], 512 B per block
    {
        float* zp = (float*)(wsb + CTXP_B) + (size_t)BATCH * P * 4096 + (size_t)blockIdx.x * 128;
#pragma unroll
        for (int mt = 0; mt < 2; mt++)
#pragma unroll
            for (int r = 0; r < 4; r++) {
                float z = zacc[mt][r];
                z += __shfl_xor(z, 1); z += __shfl_xor(z, 2);
                z += __shfl_xor(z, 4); z += __shfl_xor(z, 8);
                if (n16 == 0) zp[mt * 64 + wave * 16 + q * 4 + r] = z;
            }
    }
}

// Parallel reduce + normalize. ctx slabs are [h][d][c]; ctxb write un-transposes to
// [b][h][c][d]. z is [p][o]-contiguous; transpose absorbed via an 8x32 LDS reduction.
__global__ __launch_bounds__(256) void k_reduce(char* __restrict__ wsb, int P) {
    __shared__ float red[4][64];
    __shared__ float zred[8][33];
    const int tid = threadIdx.x;
    const int b = blockIdx.x >> 6, eg = blockIdx.x & 63;   // h = eg>>4
    const float* ctxp = (const float*)(wsb + CTXP_B);
    const float* zp = ctxp + (size_t)BATCH * P * 4096;

    // z sums: 8 p-slots x 32 channels (this block's h-group)
    {
        int ci = tid & 31, pslot = tid >> 5;
        int ho = (eg >> 4) * 32;
        float zs = 0.f;
        for (int p = pslot; p < P; p += 8)
            zs += zp[(size_t)(b * P + p) * 128 + ho + ci];
        zred[pslot][ci] = zs;
    }
    // ctx partial sums: thread (pg, e) sums P/4 slabs, coalesced across e
    {
        int pg = tid >> 6, e = tid & 63;
        int cnt = P >> 2;
        const float* base = ctxp + ((size_t)(b * P + pg * cnt)) * 4096 + eg * 64 + e;
        float cs = 0.f;
        for (int k = 0; k < cnt; k++) cs += base[(size_t)k * 4096];
        red[pg][e] = cs;
    }
    __syncthreads();
    if (tid < 64) {
        float tot = red[0][tid] + red[1][tid] + red[2][tid] + red[3][tid];
        int c = tid & 31;
        float zs = 0.f;
#pragma unroll
        for (int s = 0; s < 8; s++) zs += zred[s][c];
        int e = eg * 64 + tid;
        int h = e >> 10, d = (e >> 5) & 31;
        ((__bf16*)(wsb + CTXB_B))[((size_t)b << 12) + (h << 10) + (c << 5) + d] =
            (__bf16)(tot / zs);
    }
}

// Pass 2 (measured-best round-9 form, spill-free): q = Wq @ x; reg softmax;
// attn = ctx @ p; out = Wout @ attn + bias; GN sums; store pre-GN out.
// Grid 1024, nrep=2, rep-1 x prefetched during rep-0 compute; f32->bf16 shrink of
// the prefetch happens AFTER the attn MFMA (the empirically fastest placement).
__global__ __launch_bounds__(256, 4) void k_pass2(const float* __restrict__ x,
                                                  const float* __restrict__ bout,
                                                  char* __restrict__ wsb,
                                                  float* __restrict__ out) {
    __shared__ __attribute__((aligned(16))) __bf16 xb[8352];   // reused as attB
    __shared__ __attribute__((aligned(16))) __bf16 pB[8352];
    __shared__ float gred[8];
    const int t = threadIdx.x;
    const int lane = t & 63, wave = t >> 6;       // wave == head h
    const int n16 = lane & 15, q = lane >> 4;
    const int batch = blockIdx.x >> 7, sub = blockIdx.x & 127;
    const __bf16* __restrict__ wqb = (const __bf16*)(wsb + WQ_B);
    const __bf16* __restrict__ wob = (const __bf16*)(wsb + WO_B);
    const __bf16* __restrict__ ctxb = (const __bf16*)(wsb + CTXB_B);

    bf16x8 actx[2];
#pragma unroll
    for (int ml = 0; ml < 2; ml++)
        actx[ml] = *(const bf16x8*)&ctxb[((size_t)(batch * 4 + wave) * 32 + ml * 16 + n16) * 32 + q * 8];
    float4 bias[2];
#pragma unroll
    for (int ml = 0; ml < 2; ml++)
        bias[ml] = *(const float4*)&bout[wave * 32 + ml * 16 + q * 4];

    // prologue: stage chunk 'sub'
    {
        const float* xg = x + (size_t)(batch * SEQL + sub * 64) * NCH;
#pragma unroll
        for (int r = 0; r < 8; r++) {
            int e = t + r * 256;
            int tok = e >> 5, c4 = (e & 31) * 4;
            float4 v = ((const float4*)xg)[e];
            bf16x4 h; h.x = (__bf16)v.x; h.y = (__bf16)v.y; h.z = (__bf16)v.z; h.w = (__bf16)v.w;
            *(bf16x4*)&xb[(c4 >> 5) * 2088 + ((c4 >> 3) & 3) * 520 + tok * 8 + (c4 & 7)] = h;
        }
    }

    float s1 = 0.f, s2 = 0.f;
    bf16x4 hpre[8];

#pragma unroll
    for (int rep = 0; rep < 2; rep++) {
        const int chunk = sub + rep * 128;
        const size_t tok0 = (size_t)batch * SEQL + chunk * 64;
        __syncthreads();                    // B1: xb(rep) ready
        f32x4 qacc[2][4];
#pragma unroll
        for (int i = 0; i < 2; i++)
#pragma unroll
            for (int j = 0; j < 4; j++) qacc[i][j] = (f32x4){0.f, 0.f, 0.f, 0.f};
#pragma unroll
        for (int ks = 0; ks < 4; ks++) {
            bf16x8 aq_k[2];
#pragma unroll
            for (int ml = 0; ml < 2; ml++)
                aq_k[ml] = *(const bf16x8*)&wqb[(wave * 32 + ml * 16 + n16) * 128 + ks * 32 + q * 8];
            bf16x8 b[4];
#pragma unroll
            for (int nt = 0; nt < 4; nt++)
                b[nt] = *(const bf16x8*)&xb[ks * 2088 + q * 520 + (nt * 16 + n16) * 8];
#pragma unroll
            for (int ml = 0; ml < 2; ml++)
#pragma unroll
                for (int nt = 0; nt < 4; nt++)
                    qacc[ml][nt] = __builtin_amdgcn_mfma_f32_16x16x32_bf16(
                        aq_k[ml], b[nt], qacc[ml][nt], 0, 0, 0);
        }
        // prefetch rep-1 x while softmax/attn/Wout run
        float4 vpre[8];
        if (rep == 0) {
            const float* xg2 = x + (size_t)(batch * SEQL + (sub + 128) * 64) * NCH;
#pragma unroll
            for (int r = 0; r < 8; r++) vpre[r] = ((const float4*)xg2)[t + r * 256];
        }
#pragma unroll
        for (int nt = 0; nt < 4; nt++) {
            float ss = 0.f;
#pragma unroll
            for (int ml = 0; ml < 2; ml++)
#pragma unroll
                for (int r = 0; r < 4; r++) {
                    float e = __expf(qacc[ml][nt][r]);
                    qacc[ml][nt][r] = e;
                    ss += e;
                }
            ss += __shfl_xor(ss, 16);
            ss += __shfl_xor(ss, 32);
            float inv = 0.17677669529663687f / ss;   // (1/sqrt(32)) / denom
#pragma unroll
            for (int ml = 0; ml < 2; ml++)
#pragma unroll
                for (int r = 0; r < 4; r++) qacc[ml][nt][r] *= inv;
        }
#pragma unroll
        for (int ml = 0; ml < 2; ml++)
#pragma unroll
            for (int nt = 0; nt < 4; nt++) {
                bf16x4 h;
                h.x = (__bf16)qacc[ml][nt][0]; h.y = (__bf16)qacc[ml][nt][1];
                h.z = (__bf16)qacc[ml][nt][2]; h.w = (__bf16)qacc[ml][nt][3];
                *(bf16x4*)&pB[wave * 2088 + (ml * 2 + (q >> 1)) * 520 +
                              (nt * 16 + n16) * 8 + (q & 1) * 4] = h;
            }
        __syncthreads();                    // B2: pB ready; all xb GEMM reads done
        f32x4 aacc[2][4];
#pragma unroll
        for (int ml = 0; ml < 2; ml++)
#pragma unroll
            for (int nt = 0; nt < 4; nt++) {
                bf16x8 pb = *(const bf16x8*)&pB[wave * 2088 + q * 520 + (nt * 16 + n16) * 8];
                aacc[ml][nt] = __builtin_amdgcn_mfma_f32_16x16x32_bf16(
                    actx[ml], pb, (f32x4){0.f, 0.f, 0.f, 0.f}, 0, 0, 0);
            }
        if (rep == 0) {                     // shrink in-flight regs: f32 -> bf16
#pragma unroll
            for (int r = 0; r < 8; r++) {
                bf16x4 h;
                h.x = (__bf16)vpre[r].x; h.y = (__bf16)vpre[r].y;
                h.z = (__bf16)vpre[r].z; h.w = (__bf16)vpre[r].w;
                hpre[r] = h;
            }
        }
        __bf16* attB = xb;
#pragma unroll
        for (int ml = 0; ml < 2; ml++)
#pragma unroll
            for (int nt = 0; nt < 4; nt++) {
                bf16x4 h;
                h.x = (__bf16)aacc[ml][nt][0]; h.y = (__bf16)aacc[ml][nt][1];
                h.z = (__bf16)aacc[ml][nt][2]; h.w = (__bf16)aacc[ml][nt][3];
                *(bf16x4*)&attB[wave * 2088 + (ml * 2 + (q >> 1)) * 520 +
                                (nt * 16 + n16) * 8 + (q & 1) * 4] = h;
            }
        __syncthreads();                    // B3: attB ready
        f32x4 oacc[2][4];
#pragma unroll
        for (int i = 0; i < 2; i++)
#pragma unroll
            for (int j = 0; j < 4; j++) oacc[i][j] = (f32x4){0.f, 0.f, 0.f, 0.f};
#pragma unroll
        for (int ks = 0; ks < 4; ks++) {
            bf16x8 ao_k[2];
#pragma unroll
            for (int ml = 0; ml < 2; ml++)
                ao_k[ml] = *(const bf16x8*)&wob[(wave * 32 + ml * 16 + n16) * 128 + ks * 32 + q * 8];
            bf16x8 b[4];
#pragma unroll
            for (int nt = 0; nt < 4; nt++)
                b[nt] = *(const bf16x8*)&attB[ks * 2088 + q * 520 + (nt * 16 + n16) * 8];
#pragma unroll
            for (int ml = 0; ml < 2; ml++)
#pragma unroll
                for (int nt = 0; nt < 4; nt++)
                    oacc[ml][nt] = __builtin_amdgcn_mfma_f32_16x16x32_bf16(
                        ao_k[ml], b[nt], oacc[ml][nt], 0, 0, 0);
        }
#pragma unroll
        for (int ml = 0; ml < 2; ml++)
#pragma unroll
            for (int nt = 0; nt < 4; nt++) {
                float4 vv;
                vv.x = oacc[ml][nt][0] + bias[ml].x;
                vv.y = oacc[ml][nt][1] + bias[ml].y;
                vv.z = oacc[ml][nt][2] + bias[ml].z;
                vv.w = oacc[ml][nt][3] + bias[ml].w;
                s1 += vv.x + vv.y + vv.z + vv.w;
                s2 += vv.x * vv.x + vv.y * vv.y + vv.z * vv.z + vv.w * vv.w;
                *(float4*)&out[(tok0 + nt * 16 + n16) * NCH + wave * 32 + ml * 16 + q * 4] = vv;
            }
        if (rep == 0) {
            __syncthreads();                // B4: all attB(=xb) reads done
#pragma unroll
            for (int r = 0; r < 8; r++) {
                int e = t + r * 256;
                int tok = e >> 5, c4 = (e & 31) * 4;
                *(bf16x4*)&xb[(c4 >> 5) * 2088 + ((c4 >> 3) & 3) * 520 + tok * 8 + (c4 & 7)] = hpre[r];
            }
        }
    }
#pragma unroll
    for (int off = 32; off > 0; off >>= 1) {
        s1 += __shfl_xor(s1, off);
        s2 += __shfl_xor(s2, off);
    }
    if (lane == 0) { gred[wave * 2 + 0] = s1; gred[wave * 2 + 1] = s2; }
    __syncthreads();
    if (t < 2) {
        float s = gred[t] + gred[2 + t] + gred[4 + t] + gred[6 + t];
        atomicAdd(&((float*)(wsb + GNS_B))[batch * 2 + t], s);
    }
}

// GroupNorm apply — proven form: 2x float4/thread (50% line util per instruction),
// grid 8192. The 4x-float4 variant (25% line util) regressed ~10-15 us.
__global__ __launch_bounds__(256) void k_gnorm(float* __restrict__ out,
                                               const char* __restrict__ wsb,
                                               const float* __restrict__ gw,
                                               const float* __restrict__ gb) {
    size_t base4 = ((size_t)blockIdx.x * 256 + threadIdx.x) * 2;   // float4 index
    int b = (int)(base4 >> 19);
    const float* gns = (const float*)(wsb + GNS_B);
    const float n = (float)NCH * (float)SEQL;
    float mean = gns[b * 2] / n;
    float var = gns[b * 2 + 1] / n - mean * mean;
    float rstd = rsqrtf(var + GEPS);
    int cbase = (int)((base4 & 31) * 4);
    float4 w0 = *(const float4*)&gw[cbase];
    float4 w1 = *(const float4*)&gw[cbase + 4];
    float4 b0 = *(const float4*)&gb[cbase];
    float4 b1 = *(const float4*)&gb[cbase + 4];
    float4 v0 = ((float4*)out)[base4];
    float4 v1 = ((float4*)out)[base4 + 1];
    v0.x = (v0.x - mean) * rstd * w0.x + b0.x;
    v0.y = (v0.y - mean) * rstd * w0.y + b0.y;
    v0.z = (v0.z - mean) * rstd * w0.z + b0.z;
    v0.w = (v0.w - mean) * rstd * w0.w + b0.w;
    v1.x = (v1.x - mean) * rstd * w1.x + b1.x;
    v1.y = (v1.y - mean) * rstd * w1.y + b1.y;
    v1.z = (v1.z - mean) * rstd * w1.z + b1.z;
    v1.w = (v1.w - mean) * rstd * w1.w + b1.w;
    ((float4*)out)[base4] = v0;
    ((float4*)out)[base4 + 1] = v1;
}

extern "C" void kernel_launch(void* const* d_in, const int* in_sizes, int n_in,
                              void* d_out, int out_size, void* d_ws, size_t ws_size,
                              hipStream_t stream) {
    const float* x    = (const float*)d_in[0];
    const float* wqkv = (const float*)d_in[1];
    const float* wout = (const float*)d_in[2];
    const float* bout = (const float*)d_in[3];
    const float* gw   = (const float*)d_in[4];
    const float* gb   = (const float*)d_in[5];
    float* out = (float*)d_out;
    char* wsb  = (char*)d_ws;

    int P = 128;
    while (P > 4 &&
           (size_t)CTXP_B + (size_t)BATCH * P * (16384 + 512) > ws_size)
        P >>= 1;

    k_prep<<<192, 256, 0, stream>>>(wqkv, wout, wsb);
    k_pass1<<<BATCH * P, 256, 0, stream>>>(x, wsb, P);
    k_reduce<<<BATCH * 64, 256, 0, stream>>>(wsb, P);
    k_pass2<<<1024, 256, 0, stream>>>(x, bout, wsb, out);
    k_gnorm<<<8192, 256, 0, stream>>>(out, wsb, gw, gb);
}